// Round 14
// baseline (642.462 us; speedup 1.0000x reference)
//
#include <hip/hip_runtime.h>
#include <hip/hip_bf16.h>
#include <stdint.h>

#define NN 8192
#define DIN 512
#define DOUT 256
#define NSPLIT 8
#define STRIP (NN / NSPLIT) /* 1024 */

typedef short short8 __attribute__((ext_vector_type(8)));
typedef float floatx4 __attribute__((ext_vector_type(4)));

__device__ __forceinline__ unsigned short f2bf_rne(float x) {
  unsigned u = __float_as_uint(x);
  u += 0x7fffu + ((u >> 16) & 1u);
  return (unsigned short)(u >> 16);
}
__device__ __forceinline__ float bf2f(unsigned short h) {
  return __uint_as_float(((unsigned)h) << 16);
}

// -------- weight transpose+cvt: W fp32 [512][256] -> WT bf16 [256][512] --------
__global__ __launch_bounds__(256) void kt_transpose(const float* __restrict__ Wg,
                                                    unsigned short* __restrict__ WT) {
  __shared__ unsigned short sm[32][33];
  int tid = threadIdx.x;
  int bk = blockIdx.x >> 3;  // k tile
  int bn = blockIdx.x & 7;   // n tile
  int k0 = bk * 32, n0 = bn * 32;
  int r = tid >> 3, c4 = (tid & 7) * 4;
  const float* src = Wg + (size_t)(k0 + r) * DOUT + n0 + c4;
#pragma unroll
  for (int x = 0; x < 4; ++x) sm[r][c4 + x] = f2bf_rne(src[x]);
  __syncthreads();
  unsigned short* dst = WT + (size_t)(n0 + r) * DIN + k0 + c4;
#pragma unroll
  for (int x = 0; x < 4; ++x) dst[x] = sm[c4 + x][r];
}

// -- GEMM1 (MFMA): WhT[d][i] = sum_k X[i][k] W[k][d]; i-tile 64 -> 512 blocks --
__global__ __launch_bounds__(256) void kt_gemm1(const float* __restrict__ X,
                                                const unsigned short* __restrict__ WT,
                                                const float* __restrict__ Ab,
                                                unsigned short* __restrict__ WhT,
                                                float* __restrict__ Wh1,
                                                float* __restrict__ Wh2) {
  int tid = threadIdx.x;
  int w = tid >> 6, lane = tid & 63;
  int col = lane & 15, q = lane >> 4;
  int db = blockIdx.x & 3;   // d block (64 each)
  int ib = blockIdx.x >> 2;  // i block (64 each), 128 of them
  int i0 = ib * 64;
  int drow = db * 64 + w * 16 + col;  // A row (d), m = lane&15
  const unsigned short* abase = WT + (size_t)drow * DIN + q * 8;
  const float* xbase = X + (size_t)(i0 + col) * DIN + q * 8;
  floatx4 acc[4];
#pragma unroll
  for (int t = 0; t < 4; ++t) acc[t] = (floatx4)(0.0f);
  for (int k0 = 0; k0 < DIN; k0 += 32) {
    short8 af = *(const short8*)(abase + k0);
#pragma unroll
    for (int t = 0; t < 4; ++t) {
      const float* xp = xbase + (size_t)t * 16 * DIN + k0;
      float4 xa = *(const float4*)xp;
      float4 xb = *(const float4*)(xp + 4);
      short8 bf;
      bf[0] = (short)f2bf_rne(xa.x); bf[1] = (short)f2bf_rne(xa.y);
      bf[2] = (short)f2bf_rne(xa.z); bf[3] = (short)f2bf_rne(xa.w);
      bf[4] = (short)f2bf_rne(xb.x); bf[5] = (short)f2bf_rne(xb.y);
      bf[6] = (short)f2bf_rne(xb.z); bf[7] = (short)f2bf_rne(xb.w);
      acc[t] = __builtin_amdgcn_mfma_f32_16x16x32_bf16(af, bf, acc[t], 0, 0, 0);
    }
  }
  // D: col=lane&15 -> i; row=q*4+r -> d
  int dq = db * 64 + w * 16 + q * 4;
  float a1v[4], a2v[4];
#pragma unroll
  for (int r = 0; r < 4; ++r) { a1v[r] = Ab[dq + r]; a2v[r] = Ab[DOUT + dq + r]; }
#pragma unroll
  for (int t = 0; t < 4; ++t) {
    floatx4 v = acc[t];
    int icol = i0 + t * 16 + col;
#pragma unroll
    for (int r = 0; r < 4; ++r) WhT[(size_t)(dq + r) * NN + icol] = f2bf_rne(v[r]);
    float p1 = v[0] * a1v[0] + v[1] * a1v[1] + v[2] * a1v[2] + v[3] * a1v[3];
    float p2 = v[0] * a2v[0] + v[1] * a2v[1] + v[2] * a2v[2] + v[3] * a2v[3];
    p1 += __shfl_xor(p1, 16);
    p1 += __shfl_xor(p1, 32);
    p2 += __shfl_xor(p2, 16);
    p2 += __shfl_xor(p2, 32);
    if (q == 0) {
      atomicAdd(&Wh1[icol], p1);
      atomicAdd(&Wh2[icol], p2);
    }
  }
}

// ---------------- fused masked-softmax attention (rank-1 scores) ----------------
__device__ __forceinline__ short8 build_a(int4 pa, int4 pb, float wh1, const float* w2,
                                          float& lsum) {
  int av[8] = {pa.x, pa.y, pa.z, pa.w, pb.x, pb.y, pb.z, pb.w};
  short8 af;
#pragma unroll
  for (int e = 0; e < 8; ++e) {
    float sc = wh1 + w2[e];
    sc = fmaxf(sc, 0.2f * sc);  // LeakyReLU
    float ex = __expf(sc);
    float wv = (av[e] != 0) ? ex : 0.0f;
    unsigned short hb = f2bf_rne(wv);
    af[e] = (short)hb;
    lsum += bf2f(hb);  // denominator from the *rounded* weight
  }
  return af;
}

// NOTE: no min-waves launch-bounds arg — R11/12/13's `(256,4)` is the one
// compile-affecting delta vs the R10 pass and is the bisect target here.
__global__ __launch_bounds__(256) void kt_attn(const int* __restrict__ adj,
                                               const unsigned short* __restrict__ WhT,
                                               const float* __restrict__ Wh1,
                                               const float* __restrict__ Wh2,
                                               float* __restrict__ accg,
                                               float* __restrict__ lg) {
  __shared__ __align__(16) unsigned short tileB[2][32 * DOUT];  // 2 x 16 KB, XOR-swizzled
  __shared__ __align__(16) float wh2s[STRIP];                   // 4 KB
  int tid = threadIdx.x;
  int w = tid >> 6, lane = tid & 63;
  int col = lane & 15, q = lane >> 4;
  int s = blockIdx.x & (NSPLIT - 1);
  int ib = blockIdx.x / NSPLIT;
  int i0 = ib * 64;
  int jb = s * STRIP;
  int wr = (w >> 1) * 32;   // wave row-group offset (0 or 32)
  int dh = (w & 1) * 128;   // wave d half

  // stage Wh2 strip: 1024 floats = 256 float4, one per thread
  ((floatx4*)wh2s)[tid] = ((const floatx4*)(Wh2 + jb))[tid];

  float wh1r0 = Wh1[i0 + wr + col];
  float wh1r1 = Wh1[i0 + wr + 16 + col];

  // staging: thread owns WhT row d = tid; 32-j slice, XOR chunk swizzle
  int drow = tid;
  int fsw = (drow >> 1) & 3;
  const unsigned short* gsrc = WhT + (size_t)drow * NN + jb;
  unsigned short* lrow0 = &tileB[0][drow * 32];
  unsigned short* lrow1 = &tileB[1][drow * 32];

  // reader: row d = dh + t*16 + col, j-chunk q at physical chunk q^fc
  int fc = (col >> 1) & 3;
  const unsigned short* bbase0 = &tileB[0][(dh + col) * 32 + ((q ^ fc) * 8)];
  const unsigned short* bbase1 = &tileB[1][(dh + col) * 32 + ((q ^ fc) * 8)];

  const int* aptr0 = adj + ((size_t)(i0 + wr + col) << 13) + jb + q * 8;
  const int* aptr1 = adj + ((size_t)(i0 + wr + 16 + col) << 13) + jb + q * 8;

  floatx4 acc[2][8];
#pragma unroll
  for (int g = 0; g < 2; ++g)
#pragma unroll
    for (int t = 0; t < 8; ++t) acc[g][t] = (floatx4)(0.0f);
  float lp0 = 0.f, lp1 = 0.f;

  // prologue: tile 0 staged into buf0; tile 1 in registers; adj 2 steps deep
  short8 st[4];
#pragma unroll
  for (int m = 0; m < 4; ++m) st[m] = *(const short8*)(gsrc + m * 8);
#pragma unroll
  for (int m = 0; m < 4; ++m) *(short8*)(lrow0 + ((m ^ fsw) * 8)) = st[m];
#pragma unroll
  for (int m = 0; m < 4; ++m) st[m] = *(const short8*)(gsrc + 32 + m * 8);
  int4 s0a[2], s0b[2], s1a[2], s1b[2];  // adj regs: slot = step parity
#pragma unroll
  for (int p = 0; p < 2; ++p) {
    s0a[p] = *(const int4*)(aptr0 + p * 32);
    s0b[p] = *(const int4*)(aptr0 + p * 32 + 4);
    s1a[p] = *(const int4*)(aptr1 + p * 32);
    s1b[p] = *(const int4*)(aptr1 + p * 32 + 4);
  }

  const int NSTEP = STRIP / 32;  // 32
#pragma unroll 1
  for (int k = 0; k < NSTEP; ++k) {
    int jl = k * 32;
    __syncthreads();  // buf[k&1] writes visible; prev-step reads of buf[(k+1)&1] done
    if (k + 1 < NSTEP) {  // stage tile k+1 into the idle buffer
      unsigned short* lw = (k & 1) ? lrow0 : lrow1;
#pragma unroll
      for (int m = 0; m < 4; ++m) *(short8*)(lw + ((m ^ fsw) * 8)) = st[m];
      if (k + 2 < NSTEP) {  // register prefetch of tile k+2
#pragma unroll
        for (int m = 0; m < 4; ++m) st[m] = *(const short8*)(gsrc + (jl + 64) + m * 8);
      }
    }
    const unsigned short* bb = (k & 1) ? bbase1 : bbase0;
    short8 bf[8];
#pragma unroll
    for (int t = 0; t < 8; ++t) bf[t] = *(const short8*)(bb + t * 512);
    floatx4 w2a = *(const floatx4*)&wh2s[jl + q * 8];
    floatx4 w2b = *(const floatx4*)&wh2s[jl + q * 8 + 4];
    float w2[8] = {w2a[0], w2a[1], w2a[2], w2a[3], w2b[0], w2b[1], w2b[2], w2b[3]};
    int p = k & 1;
    short8 af0 = build_a(s0a[p], s0b[p], wh1r0, w2, lp0);
    short8 af1 = build_a(s1a[p], s1b[p], wh1r1, w2, lp1);
    if (k + 2 < NSTEP) {  // adj prefetch 2 steps ahead into the freed slot
      s0a[p] = *(const int4*)(aptr0 + jl + 64);
      s0b[p] = *(const int4*)(aptr0 + jl + 68);
      s1a[p] = *(const int4*)(aptr1 + jl + 64);
      s1b[p] = *(const int4*)(aptr1 + jl + 68);
    }
#pragma unroll
    for (int t = 0; t < 8; ++t)
      acc[0][t] = __builtin_amdgcn_mfma_f32_16x16x32_bf16(af0, bf[t], acc[0][t], 0, 0, 0);
#pragma unroll
    for (int t = 0; t < 8; ++t)
      acc[1][t] = __builtin_amdgcn_mfma_f32_16x16x32_bf16(af1, bf[t], acc[1][t], 0, 0, 0);
  }

  // l reduction across q groups; one atomic per row per strip (dh=0 waves only)
  lp0 += __shfl_xor(lp0, 16);
  lp0 += __shfl_xor(lp0, 32);
  lp1 += __shfl_xor(lp1, 16);
  lp1 += __shfl_xor(lp1, 32);
  if (((w & 1) == 0) && lane < 16) {
    atomicAdd(&lg[i0 + wr + lane], lp0);
    atomicAdd(&lg[i0 + wr + 16 + lane], lp1);
  }
  // fp32 partial merge via coalesced atomics (8 strips per address)
#pragma unroll
  for (int g = 0; g < 2; ++g) {
#pragma unroll
    for (int t = 0; t < 8; ++t) {
      floatx4 v = acc[g][t];
      int dcol = dh + t * 16 + col;
      int irow = i0 + wr + g * 16 + q * 4;
#pragma unroll
      for (int r = 0; r < 4; ++r) atomicAdd(&accg[(size_t)(irow + r) * DOUT + dcol], v[r]);
    }
  }
}

// ---------------- normalize + ELU -> fp32 out ----------------
__global__ __launch_bounds__(256) void kt_merge(const float* __restrict__ accg,
                                               const float* __restrict__ lg,
                                               float* __restrict__ out) {
  int i = blockIdx.x;
  int d = threadIdx.x;
  size_t idx = (size_t)i * DOUT + d;
  float x = accg[idx] / lg[i];
  x = x > 0.f ? x : (__expf(x) - 1.f);
  out[idx] = x;
}

extern "C" void kernel_launch(void* const* d_in, const int* in_sizes, int n_in,
                              void* d_out, int out_size, void* d_ws, size_t ws_size,
                              hipStream_t stream) {
  const float* X = (const float*)d_in[0];       // input fp32 [8192][512]
  const int* adj = (const int*)d_in[1];         // int32 [8192][8192]
  const float* Wg = (const float*)d_in[2];      // weight fp32 [512][256]
  const float* Ab = (const float*)d_in[3];      // a fp32 [512]
  float* out = (float*)d_out;                   // fp32 [8192][256]

  // workspace: accg | lg | Wh1 | Wh2 | WT | WhT  (~12.4 MB)
  char* ws = (char*)d_ws;
  float* accg = (float*)ws;                                  // 8 MB
  size_t off = (size_t)NN * DOUT * 4;
  float* lg = (float*)(ws + off);  off += (size_t)NN * 4;
  float* Wh1 = (float*)(ws + off); off += (size_t)NN * 4;
  float* Wh2 = (float*)(ws + off); off += (size_t)NN * 4;
  size_t zero_bytes = off;                                   // accg+lg+Wh1+Wh2
  unsigned short* WT = (unsigned short*)(ws + off);
  off += (size_t)DOUT * DIN * 2;                             // 256 KB
  unsigned short* WhT = (unsigned short*)(ws + off);
  off += (size_t)DOUT * NN * 2;                              // 4 MB

  hipMemsetAsync(accg, 0, zero_bytes, stream);  // zero atomic accumulators
  kt_transpose<<<128, 256, 0, stream>>>(Wg, WT);
  kt_gemm1<<<(NN / 64) * 4, 256, 0, stream>>>(X, WT, Ab, WhT, Wh1, Wh2);
  kt_attn<<<(NN / 64) * NSPLIT, 256, 0, stream>>>(adj, WhT, Wh1, Wh2, accg, lg);
  kt_merge<<<NN, 256, 0, stream>>>(accg, lg, out);
}